// Round 11
// baseline (343.144 us; speedup 1.0000x reference)
//
#include <hip/hip_runtime.h>
#include <cstdint>
#include <cstddef>

typedef float   f32x4 __attribute__((ext_vector_type(4)));
typedef _Float16 f16x8 __attribute__((ext_vector_type(8)));
typedef _Float16 f16x4 __attribute__((ext_vector_type(4)));

#define TOK  4096   // B*S tokens
#define HID  1024
#define IDIM 4096

// direct global->LDS async copy, 16 B per lane (wave-uniform LDS base + lane*16)
#define GLDS16(gp, lp) __builtin_amdgcn_global_load_lds(                      \
    (const __attribute__((address_space(1))) void*)(gp),                      \
    (__attribute__((address_space(3))) void*)(lp), 16, 0, 0)

// LDS tile layouts (both-sides-or-neither swizzle: source perm == read perm):
//  BK=32 (gemm_dense): slot(row,kh) = row*4 + (kh ^ ((row>>1)&3)), kh 0..3.
//  BK=64 (gemm_w32):   slot(row,kh) = row*8 + (kh ^ (row&7)),      kh 0..7.
//
// Occupancy lessons: R5 — 256-blk/256-thr = 1 blk/CU = dead. R6 — 7-blk prep
// = 77us. R7/R9 — prep GEMMs via split-K gemm_dense (>=128 blks). R10 —
// gemm_w32 BK=64 (8 MFMA/barrier-pair). R11 — value-fold: fuse =
// h@Wv^T + wdown@WVU^T + probs@BVU + it (MODE 6 two-phase GEMM); `mixed`
// and f32 h eliminated.

// ---------------------------------------------------------------------------
// Split-K GEMM core: 128x128 tile, BK=32, 256 thr = 4 waves (2x2), wave 64x64
// (4x4 MFMA 16x16x32 f16). fp32 partials at part + z*zstride, row stride nstride.
// ---------------------------------------------------------------------------
__global__ __launch_bounds__(256, 4) void gemm_dense(
    const _Float16* __restrict__ A, const _Float16* __restrict__ B,
    int K, int Kchunk, float* __restrict__ part, size_t zstride, int nstride)
{
    __shared__ _Float16 lA[2][4096];
    __shared__ _Float16 lB[2][4096];
    const int tid  = threadIdx.x;
    const int lane = tid & 63;
    const int wave = tid >> 6;
    const int m0   = blockIdx.x * 128;
    const int n0   = blockIdx.y * 128;
    const int kz0  = blockIdx.z * Kchunk;
    const int wM   = (wave & 1) * 64;
    const int wN   = (wave >> 1) * 64;

    const int srow = lane >> 2;
    const int scol = ((lane & 3) ^ ((lane >> 3) & 3)) * 8;   // swizzled kh
    const _Float16* gA0 = A + (size_t)(m0 + wave * 32 + srow) * K + kz0 + scol;
    const _Float16* gA1 = gA0 + (size_t)16 * K;
    const _Float16* gB0 = B + (size_t)(n0 + wave * 32 + srow) * K + kz0 + scol;
    const _Float16* gB1 = gB0 + (size_t)16 * K;
    const int soff = wave * 1024;

    f32x4 acc[4][4] = {};
    const int fr  = lane & 15;
    const int khr = lane >> 4;
    const int kxo = (khr ^ ((fr >> 1) & 3)) * 8;

    GLDS16(gA0, &lA[0][soff]);
    GLDS16(gA1, &lA[0][soff + 512]);
    GLDS16(gB0, &lB[0][soff]);
    GLDS16(gB1, &lB[0][soff + 512]);
    __syncthreads();

    int cur = 0;
    for (int k = 0; k < Kchunk; k += 32) {
        if (k + 32 < Kchunk) {
            const int nb = cur ^ 1;
            GLDS16(gA0 + k + 32, &lA[nb][soff]);
            GLDS16(gA1 + k + 32, &lA[nb][soff + 512]);
            GLDS16(gB0 + k + 32, &lB[nb][soff]);
            GLDS16(gB1 + k + 32, &lB[nb][soff + 512]);
        }
        f16x8 afr[4], bfr[4];
#pragma unroll
        for (int mi = 0; mi < 4; ++mi)
            afr[mi] = *(const f16x8*)(&lA[cur][(wM + mi * 16 + fr) * 32 + kxo]);
#pragma unroll
        for (int ni = 0; ni < 4; ++ni)
            bfr[ni] = *(const f16x8*)(&lB[cur][(wN + ni * 16 + fr) * 32 + kxo]);
#pragma unroll
        for (int mi = 0; mi < 4; ++mi)
#pragma unroll
            for (int ni = 0; ni < 4; ++ni)
                acc[mi][ni] = __builtin_amdgcn_mfma_f32_16x16x32_f16(
                    afr[mi], bfr[ni], acc[mi][ni], 0, 0, 0);
        __syncthreads();
        cur ^= 1;
    }

    float* dst = part + (size_t)blockIdx.z * zstride;
    const int cn = lane & 15;
    const int rq = (lane >> 4) * 4;
#pragma unroll
    for (int mi = 0; mi < 4; ++mi)
#pragma unroll
        for (int r = 0; r < 4; ++r) {
            const int m = m0 + wM + mi * 16 + rq + r;
#pragma unroll
            for (int ni = 0; ni < 4; ++ni) {
                const int n = n0 + wN + ni * 16 + cn;
                dst[(size_t)m * nstride + n] = acc[mi][ni][r];
            }
        }
}

// out_f16[i] = f16(sum_z in[z*zstride + i]),  n4 = elems/4, grid-stride
__global__ __launch_bounds__(256) void reduce_sk(
    const float* __restrict__ in, size_t zstride4, int sk,
    _Float16* __restrict__ outp, int n4)
{
    const int gid = blockIdx.x * 256 + threadIdx.x;
    const int gsz = gridDim.x * 256;
    for (int i = gid; i < n4; i += gsz) {
        f32x4 v = ((const f32x4*)in)[i];
        for (int z = 1; z < sk; ++z)
            v += ((const f32x4*)in)[z * zstride4 + i];
        f16x4 o;
        o[0] = (_Float16)v[0]; o[1] = (_Float16)v[1];
        o[2] = (_Float16)v[2]; o[3] = (_Float16)v[3];
        ((f16x4*)outp)[i] = o;
    }
}

// BK=64 compute step: 2 k-halves x 2x2 MFMA from swizzled 8-slot rows
__device__ __forceinline__ void mma64(
    const _Float16* __restrict__ lAc, const _Float16* __restrict__ lBc,
    int wM, int wN, int fr, int khr, f32x4 acc[2][2])
{
#pragma unroll
    for (int kk = 0; kk < 2; ++kk) {
        f16x8 afr[2], bfr[2];
#pragma unroll
        for (int mi = 0; mi < 2; ++mi) {
            const int row = wM + mi * 16 + fr;
            afr[mi] = *(const f16x8*)(
                &lAc[(row * 8 + ((kk * 4 + khr) ^ (row & 7))) * 8]);
        }
#pragma unroll
        for (int ni = 0; ni < 2; ++ni) {
            const int row = wN + ni * 16 + fr;
            bfr[ni] = *(const f16x8*)(
                &lBc[(row * 8 + ((kk * 4 + khr) ^ (row & 7))) * 8]);
        }
#pragma unroll
        for (int mi = 0; mi < 2; ++mi)
#pragma unroll
            for (int ni = 0; ni < 2; ++ni)
                acc[mi][ni] = __builtin_amdgcn_mfma_f32_16x16x32_f16(
                    afr[mi], bfr[ni], acc[mi][ni], 0, 0, 0);
    }
}

// ---------------------------------------------------------------------------
// Small-K GEMM: 1024 thr = 16 waves (4x4), wave 32x32 (2x2 MFMA), 128x128
// tile, BK=64, swizzled-slot LDS, 2-phase double-buffer.
// MODE 5: dual N=512: by<4 -> down=relu(Ah@B^T+bias); by>=4 -> g=A2@B2^T+upb[n]
// MODE 6: value-fold: outF = Ah@B^T (K) + A2@B2^T (512) + addv + probs@upb
// ---------------------------------------------------------------------------
template <int MODE>
__global__ __launch_bounds__(1024, 4) void gemm_w32(
    const _Float16* __restrict__ Ah, const _Float16* __restrict__ B,
    int K, int Ncols,
    float* __restrict__ outF, _Float16* __restrict__ outH,
    const float* __restrict__ bias, const float* __restrict__ addv,
    const float* __restrict__ probs, const float* __restrict__ upb,
    const _Float16* __restrict__ A2, const _Float16* __restrict__ B2,
    _Float16* __restrict__ outH2)
{
    __shared__ _Float16 lA[2][8192];
    __shared__ _Float16 lB[2][8192];
    const int tid  = threadIdx.x;
    const int lane = tid & 63;
    const int wave = tid >> 6;
    const int m0   = blockIdx.x * 128;
    int n0, half = 0;
    const _Float16* Ap = Ah;
    const _Float16* Bp = B;
    if constexpr (MODE == 5) {
        half = blockIdx.y >> 2;
        n0 = (blockIdx.y & 3) * 128;
        if (half) { Ap = A2; Bp = B2; }
    } else {
        n0 = blockIdx.y * 128;
    }
    const int wM = (wave & 3) * 32;
    const int wN = (wave >> 2) * 32;

    f32x4 acc[2][2] = {};

    // waves 0-7 stage A rows 16*i8..16*i8+15 (2 issues of 8 rows); 8-15: B.
    const int i8   = wave & 7;
    const int srow = lane >> 3;                              // 0..7
    const int scol = ((lane & 7) ^ ((lane >> 3) & 7)) * 8;   // swizzled kh
    _Float16* ldst = ((wave < 8) ? &lA[0][0] : &lB[0][0]) + i8 * 1024;
    const int fr  = lane & 15;
    const int khr = lane >> 4;   // 0..3

    int cur = 0;
    {   // phase 1 (MODE5: only phase): Ap (stride K) x Bp (stride K)
        const _Float16* gsrc = ((wave < 8)
            ? Ap + (size_t)(m0 + i8 * 16 + srow) * K
            : Bp + (size_t)(n0 + i8 * 16 + srow) * K) + scol;
        const size_t g8K = (size_t)8 * K;
        GLDS16(gsrc, ldst);
        GLDS16(gsrc + g8K, ldst + 512);
        __syncthreads();
        for (int k0 = 0; k0 < K; k0 += 64) {
            if (k0 + 64 < K) {
                _Float16* nd = ldst + (cur ^ 1) * 8192;
                GLDS16(gsrc + k0 + 64, nd);
                GLDS16(gsrc + k0 + 64 + g8K, nd + 512);
            }
            mma64(&lA[cur][0], &lB[cur][0], wM, wN, fr, khr, acc);
            __syncthreads();
            cur ^= 1;
        }
    }
    if constexpr (MODE == 6) {
        // phase 2: A2 (stride 512) x B2 (stride 512), accumulate same acc
        const _Float16* gsrc = ((wave < 8)
            ? A2 + (size_t)(m0 + i8 * 16 + srow) * 512
            : B2 + (size_t)(n0 + i8 * 16 + srow) * 512) + scol;
        GLDS16(gsrc, ldst + cur * 8192);
        GLDS16(gsrc + 8 * 512, ldst + cur * 8192 + 512);
        __syncthreads();
        for (int k0 = 0; k0 < 512; k0 += 64) {
            if (k0 + 64 < 512) {
                _Float16* nd = ldst + (cur ^ 1) * 8192;
                GLDS16(gsrc + k0 + 64, nd);
                GLDS16(gsrc + k0 + 64 + 8 * 512, nd + 512);
            }
            mma64(&lA[cur][0], &lB[cur][0], wM, wN, fr, khr, acc);
            __syncthreads();
            cur ^= 1;
        }
    }

    const int cn = lane & 15;
    const int rq = (lane >> 4) * 4;
#pragma unroll
    for (int mi = 0; mi < 2; ++mi)
#pragma unroll
        for (int r = 0; r < 4; ++r) {
            const int m = m0 + wM + mi * 16 + rq + r;
            float pr8[8];
            if constexpr (MODE == 6) {
#pragma unroll
                for (int t = 0; t < 8; ++t) pr8[t] = probs[(size_t)m * 8 + t];
            }
#pragma unroll
            for (int ni = 0; ni < 2; ++ni) {
                const int n = n0 + wN + ni * 16 + cn;
                const float v = acc[mi][ni][r];
                if constexpr (MODE == 6) {
                    const size_t idx = (size_t)m * Ncols + n;
                    float s = v + addv[idx];
#pragma unroll
                    for (int t = 0; t < 8; ++t)
                        s += pr8[t] * upb[t * 1024 + n];
                    outF[idx] = s;
                } else {  // MODE 5
                    const size_t idx = (size_t)m * 512 + n;
                    if (half == 0) {
                        const float y = v + bias[n];
                        outH[idx] = (_Float16)(y > 0.f ? y : 0.f);
                    } else {
                        outH2[idx] = (_Float16)(v + upb[n]);
                    }
                }
            }
        }
}

// ---------------------------------------------------------------------------
// fused split-K reduce + bias + LN: h = sum_z part[z] + dense_b;
// prenorm = h + it; ai = LN(prenorm); emits h(f16), ai(f16), pn(f16)
// ---------------------------------------------------------------------------
__global__ __launch_bounds__(256) void ln_fused(
    const float* __restrict__ part, int sk,
    const float* __restrict__ dbias, const float* __restrict__ it,
    const float* __restrict__ gam, const float* __restrict__ bet,
    _Float16* __restrict__ hh, _Float16* __restrict__ ai, _Float16* __restrict__ pn)
{
    const int n = blockIdx.x, tid = threadIdx.x;
    const int lane = tid & 63, wave = tid >> 6;
    const size_t base = (size_t)n * 1024 + tid * 4;
    f32x4 h = *(const f32x4*)(dbias + tid * 4);
    for (int z = 0; z < sk; ++z)
        h += *(const f32x4*)(part + (size_t)z * TOK * HID + base);
    f16x4 hv;
#pragma unroll
    for (int j = 0; j < 4; ++j) hv[j] = (_Float16)h[j];
    *(f16x4*)(hh + base) = hv;
    f32x4 x = h + *(const f32x4*)(it + base);
    float s = x[0] + x[1] + x[2] + x[3];
    float q = x[0] * x[0] + x[1] * x[1] + x[2] * x[2] + x[3] * x[3];
#pragma unroll
    for (int off = 1; off < 64; off <<= 1) {
        s += __shfl_xor(s, off);
        q += __shfl_xor(q, off);
    }
    __shared__ float rs[4], rq[4];
    if (lane == 0) { rs[wave] = s; rq[wave] = q; }
    __syncthreads();
    s = rs[0] + rs[1] + rs[2] + rs[3];
    q = rq[0] + rq[1] + rq[2] + rq[3];
    const float mu = s * (1.f / 1024.f);
    const float var = q * (1.f / 1024.f) - mu * mu;
    const float rstd = rsqrtf(var + 1e-12f);
    f32x4 gv = *(const f32x4*)(gam + tid * 4);
    f32x4 bv = *(const f32x4*)(bet + tid * 4);
    f16x4 av, pv;
#pragma unroll
    for (int j = 0; j < 4; ++j) {
        const float y = (x[j] - mu) * rstd * gv[j] + bv[j];
        av[j] = (_Float16)y;
        pv[j] = (_Float16)x[j];
    }
    *(f16x4*)(ai + base) = av;
    *(f16x4*)(pn + base) = pv;
}

// final LN: out = LN(fuse) where fuse already = input_tensor + fusion
__global__ __launch_bounds__(256) void ln_out(
    const float* __restrict__ fuse, const float* __restrict__ gam,
    const float* __restrict__ bet, float* __restrict__ outp)
{
    const int n = blockIdx.x, tid = threadIdx.x;
    const int lane = tid & 63, wave = tid >> 6;
    const size_t base = (size_t)n * 1024 + tid * 4;
    f32x4 x = *(const f32x4*)(fuse + base);
    float s = x[0] + x[1] + x[2] + x[3];
    float q = x[0] * x[0] + x[1] * x[1] + x[2] * x[2] + x[3] * x[3];
#pragma unroll
    for (int off = 1; off < 64; off <<= 1) {
        s += __shfl_xor(s, off);
        q += __shfl_xor(q, off);
    }
    __shared__ float rs[4], rq[4];
    if (lane == 0) { rs[wave] = s; rq[wave] = q; }
    __syncthreads();
    s = rs[0] + rs[1] + rs[2] + rs[3];
    q = rq[0] + rq[1] + rq[2] + rq[3];
    const float mu = s * (1.f / 1024.f);
    const float var = q * (1.f / 1024.f) - mu * mu;
    const float rstd = rsqrtf(var + 1e-12f);
    f32x4 gv = *(const f32x4*)(gam + tid * 4);
    f32x4 bv = *(const f32x4*)(bet + tid * 4);
    f32x4 y;
#pragma unroll
    for (int j = 0; j < 4; ++j) y[j] = (x[j] - mu) * rstd * gv[j] + bv[j];
    *(f32x4*)(outp + base) = y;
}

// ---------------------------------------------------------------------------
// scores + softmax over T + wdown = probs * down, per token.
// score[t] (up to a t-independent constant) = down.g + pn.WU[t] + cu[t]
// ---------------------------------------------------------------------------
__global__ __launch_bounds__(256) void scores_softmax(
    const _Float16* __restrict__ pn, const float* __restrict__ WU,
    const float* __restrict__ cu,
    const _Float16* __restrict__ down, const _Float16* __restrict__ g,
    float* __restrict__ probs_out, _Float16* __restrict__ wdown)
{
    const int n = blockIdx.x, tid = threadIdx.x;
    const int lane = tid & 63, wave = tid >> 6;
    const _Float16* pnrow = pn + (size_t)n * 1024;
    float ub[8] = {};
#pragma unroll
    for (int j = 0; j < 4; ++j) {
        const int h = tid + j * 256;
        const float pv = (float)pnrow[h];
#pragma unroll
        for (int t = 0; t < 8; ++t) ub[t] += pv * WU[t * 1024 + h];
    }
#pragma unroll
    for (int off = 1; off < 64; off <<= 1) {
#pragma unroll
        for (int t = 0; t < 8; ++t) ub[t] += __shfl_xor(ub[t], off);
    }
    __shared__ float red[4][9];
    __shared__ float sd[8];
    __shared__ float pl[8];
    if (lane == 0) {
#pragma unroll
        for (int t = 0; t < 8; ++t) red[wave][t] = ub[t];
    }
    const int c0 = tid * 2;
    const size_t dbase = (size_t)n * 512;
    const float d0 = (float)down[dbase + c0];
    const float d1 = (float)down[dbase + c0 + 1];
    float pz = d0 * (float)g[dbase + c0] + d1 * (float)g[dbase + c0 + 1];
#pragma unroll
    for (int off = 1; off < 32; off <<= 1) pz += __shfl_xor(pz, off);
    if ((lane & 31) == 0) sd[wave * 2 + (lane >> 5)] = pz;
    __syncthreads();
    if (tid == 0) {
        float sc[8];
        float mx = -1e30f;
#pragma unroll
        for (int t = 0; t < 8; ++t) {
            sc[t] = sd[t] + cu[t] + red[0][t] + red[1][t] + red[2][t] + red[3][t];
            mx = fmaxf(mx, sc[t]);
        }
        float sum = 0.f;
#pragma unroll
        for (int t = 0; t < 8; ++t) { sc[t] = expf(sc[t] - mx); sum += sc[t]; }
        const float inv = 1.f / sum;
#pragma unroll
        for (int t = 0; t < 8; ++t) pl[t] = sc[t] * inv;
    }
    __syncthreads();
    const float pr = pl[c0 >> 6];
    wdown[dbase + c0]     = (_Float16)(pr * d0);
    wdown[dbase + c0 + 1] = (_Float16)(pr * d1);
    if (tid < 8) probs_out[(size_t)n * 8 + tid] = pl[tid];
}

// ---------------------------------------------------------------------------
// weight-prep helpers
// ---------------------------------------------------------------------------
__device__ inline void cvt_seg(const float* __restrict__ s, _Float16* __restrict__ d,
                               int n4, int gid, int gsz)
{
    for (int i = gid; i < n4; i += gsz) {
        f32x4 v = ((const f32x4*)s)[i];
        f16x4 o;
        o[0] = (_Float16)v[0]; o[1] = (_Float16)v[1];
        o[2] = (_Float16)v[2]; o[3] = (_Float16)v[3];
        ((f16x4*)d)[i] = o;
    }
}

__global__ __launch_bounds__(256) void convert4(
    const float* s0, _Float16* d0, int n0,
    const float* s1, _Float16* d1, int n1,
    const float* s2, _Float16* d2, int n2,
    const float* s3, _Float16* d3, int n3,
    float* bz)   // zero 1024-float accumulator for bfuse
{
    if (blockIdx.x == 0) {
        f32x4 z = {0.f, 0.f, 0.f, 0.f};
        *(f32x4*)(bz + threadIdx.x * 4) = z;
    }
    const int gid = blockIdx.x * 256 + threadIdx.x;
    const int gsz = gridDim.x * 256;
    cvt_seg(s0, d0, n0, gid, gsz);
    cvt_seg(s1, d1, n1, gid, gsz);
    cvt_seg(s2, d2, n2, gid, gsz);
    cvt_seg(s3, d3, n3, gid, gsz);
}

// merged prep (grid 4096): b<1024 key-transpose (+bfuse), b<2048
// query-transpose, b<4096 reshape up_w -> upg.
__global__ __launch_bounds__(256) void prep_misc(
    const float* __restrict__ key_w, _Float16* __restrict__ w_keyT,
    const float* __restrict__ query_w, _Float16* __restrict__ w_queryT,
    const float* __restrict__ query_b, float* __restrict__ bfuse,
    const float* __restrict__ up_w, _Float16* __restrict__ upg)
{
    __shared__ float t[32][33];
    __shared__ float rpart[8][33];
    const int b = blockIdx.x;
    if (b < 2048) {
        const int bb = (b < 1024) ? b : b - 1024;
        const int bx = (bb & 31) * 32;   // h
        const int by = (bb >> 5) * 32;   // k
        const float* in = (b < 1024) ? key_w : query_w;
        _Float16* outp  = (b < 1024) ? w_keyT : w_queryT;
        const int tx = threadIdx.x & 31, ty = threadIdx.x >> 5;
#pragma unroll
        for (int j = 0; j < 32; j += 8)
            t[ty + j][tx] = in[(size_t)(by + ty + j) * 1024 + bx + tx];
        __syncthreads();
#pragma unroll
        for (int j = 0; j < 32; j += 8)
            outp[(size_t)(bx + ty + j) * 1024 + by + tx] = (_Float16)t[tx][ty + j];
        if (b < 1024) {
            float s = 0.f;
#pragma unroll
            for (int j = 0; j < 4; ++j) {
                const int k = ty * 4 + j;
                s += query_b[by + k] * t[k][tx];
            }
            rpart[ty][tx] = s;
            __syncthreads();
            if (ty == 0) {
                float v = rpart[0][tx];
#pragma unroll
                for (int r = 1; r < 8; ++r) v += rpart[r][tx];
                atomicAdd(bfuse + bx + tx, v);
            }
        }
    } else {
        const int i = (b - 2048) * 256 + threadIdx.x;
        const int d = i & 63;
        const int h = (i >> 6) & 1023;
        const int t8 = i >> 16;
        upg[(size_t)(t8 * 64 + d) * 1024 + h] = (_Float16)up_w[i];
    }
}

// score/value-fold vectors, fully parallel (2568 blocks x 256 thr):
//  b<1024:        WU[t][b]   = sum_h WF[b][h]   * up_b[t][h]
//  1024<=b<2048:  BVU[t][v]  = sum_h Wv[v][h]   * up_b[t][h]   (v=b-1024)
//  2048<=b<2560:  bg[b-2048] = sum_h upg[..][h] * bfuse[h]
//  2560<=b<2568:  cu[b-2560] = sum_h bfuse[h]   * up_b[..][h]
__global__ __launch_bounds__(256) void score_weights(
    const _Float16* __restrict__ wfuse, const _Float16* __restrict__ wval,
    const _Float16* __restrict__ upg, const float* __restrict__ up_b,
    const float* __restrict__ bfuse,
    float* __restrict__ WU, float* __restrict__ BVU,
    float* __restrict__ bg, float* __restrict__ cu)
{
    const int b = blockIdx.x, tid = threadIdx.x;
    const int lane = tid & 63, wave = tid >> 6;
    __shared__ float red[4][8];
    if (b < 2048) {
        const _Float16* row = (b < 1024)
            ? wfuse + (size_t)b * 1024
            : wval  + (size_t)(b - 1024) * 1024;
        const f16x4 w = *(const f16x4*)(row + tid * 4);
        float a[8] = {};
#pragma unroll
        for (int j = 0; j < 4; ++j) {
            const float wv = (float)w[j];
            const int hp = tid * 4 + j;
#pragma unroll
            for (int t = 0; t < 8; ++t) a[t] += wv * up_b[t * 1024 + hp];
        }
#pragma unroll
        for (int off = 1; off < 64; off <<= 1) {
#pragma unroll
            for (int t = 0; t < 8; ++t) a[t] += __shfl_xor(a[t], off);
        }
        if (lane == 0) {
#pragma unroll
            for (int t = 0; t < 8; ++t) red[wave][t] = a[t];
        }
        __syncthreads();
        if (tid < 8) {
            const float tot = red[0][tid] + red[1][tid] + red[2][tid] + red[3][tid];
            if (b < 1024) WU[tid * 1024 + b] = tot;
            else          BVU[tid * 1024 + (b - 1024)] = tot;
        }
    } else {
        float s;
        if (b < 2560) {
            const int td = b - 2048;
            const f16x4 w = *(const f16x4*)(upg + (size_t)td * 1024 + tid * 4);
            const f32x4 v = *(const f32x4*)(bfuse + tid * 4);
            s = (float)w[0] * v[0] + (float)w[1] * v[1]
              + (float)w[2] * v[2] + (float)w[3] * v[3];
        } else {
            const int t = b - 2560;
            const f32x4 u = *(const f32x4*)(up_b + (size_t)t * 1024 + tid * 4);
            const f32x4 v = *(const f32x4*)(bfuse + tid * 4);
            s = u[0] * v[0] + u[1] * v[1] + u[2] * v[2] + u[3] * v[3];
        }
#pragma unroll
        for (int off = 1; off < 64; off <<= 1) s += __shfl_xor(s, off);
        if (lane == 0) red[wave][0] = s;
        __syncthreads();
        if (tid == 0) {
            const float tot = red[0][0] + red[1][0] + red[2][0] + red[3][0];
            if (b < 2560) bg[b - 2048] = tot;
            else          cu[b - 2560] = tot;
        }
    }
}

// ---------------------------------------------------------------------------
extern "C" void kernel_launch(void* const* d_in, const int* in_sizes, int n_in,
                              void* d_out, int out_size, void* d_ws, size_t ws_size,
                              hipStream_t stream)
{
    const float* hs      = (const float*)d_in[0];
    const float* it      = (const float*)d_in[1];
    const float* dense_w = (const float*)d_in[2];
    const float* dense_b = (const float*)d_in[3];
    const float* ln_g    = (const float*)d_in[4];
    const float* ln_b    = (const float*)d_in[5];
    const float* down_w  = (const float*)d_in[6];
    const float* down_b  = (const float*)d_in[7];
    const float* up_w    = (const float*)d_in[8];
    const float* up_b    = (const float*)d_in[9];
    const float* key_w   = (const float*)d_in[10];
    const float* key_b   = (const float*)d_in[11];
    const float* query_w = (const float*)d_in[12];
    const float* query_b = (const float*)d_in[13];
    const float* value_w = (const float*)d_in[14];
    float* outp = (float*)d_out;
    (void)in_sizes; (void)n_in; (void)out_size; (void)key_b;

    const size_t MiB = 1ull << 20;
    // persistent region (53 MiB)
    char* p = (char*)d_ws;
    _Float16* w_dense  = (_Float16*)p; p += 8 * MiB;
    _Float16* w_queryT = (_Float16*)p; p += 2 * MiB;   // query_w^T [h,q] f16
    _Float16* w_keyT   = (_Float16*)p; p += 2 * MiB;   // key_w^T [h',q] f16
    _Float16* w_value  = (_Float16*)p; p += 2 * MiB;
    _Float16* w_fuseM  = (_Float16*)p; p += 2 * MiB;   // WF[h,h'] row-major f16
    _Float16* w_wg     = (_Float16*)p; p += 1 * MiB;   // WG[td,h] f16 (512x1024)
    _Float16* w_wvu    = (_Float16*)p; p += 1 * MiB;   // WVU[v,td] f16 (1024x512)
    _Float16* w_down   = (_Float16*)p; p += 1 * MiB;
    _Float16* w_upg    = (_Float16*)p; p += 1 * MiB;
    float*    bfuse    = (float*)p;    p += 1 * MiB;   // [0..4K) bfuse
    float*    WU       = bfuse + 1024;                 // 32 KB
    float*    bg       = WU + 8 * 1024;                // 2 KB
    float*    cu       = bg + 512;                     // 32 B
    float*    BVU      = cu + 8;                       // 32 KB
    char*     hslot    = p;            p += 16 * MiB;  // h_h uses first 8 MiB
    _Float16* h_h      = (_Float16*)hslot;
    _Float16* ai       = (_Float16*)p; p += 8 * MiB;
    _Float16* pn       = (_Float16*)p; p += 8 * MiB;
    // hs_h (32 MiB) aliases hslot+ai+pn: dead before ln_fused writes them
    _Float16* hs_h = (_Float16*)hslot;
    // region B: prep partials / split-K partials first, then activations
    char* rb = p;
    const int sk = (ws_size >= (size_t)(53 + 64) * MiB) ? 4 : 2;
    float*    prep  = (float*)rb;                 // 16 MiB (dead before part)
    float*    part  = (float*)rb;                 // sk * 16 MiB
    _Float16* down  = (_Float16*)(rb + 16 * MiB); // 4 MiB   (part dead by then)
    _Float16* g     = (_Float16*)(rb + 20 * MiB); // 4 MiB
    _Float16* wdown = (_Float16*)(rb + 24 * MiB); // 4 MiB
    float*    probs = (float*)(rb + 28 * MiB);    // 128 KiB
    float*    fuse  = (float*)rb;                 // 16 MiB (part z0 dead)

    // weight prep + hs fp32->f16; zero bfuse (block 0)
    convert4<<<2048, 256, 0, stream>>>(hs, hs_h, TOK * IDIM / 4,
                                       dense_w, w_dense, HID * IDIM / 4,
                                       value_w, w_value, HID * HID / 4,
                                       down_w,  w_down,  512 * HID / 4,
                                       bfuse);
    // keyT (+bfuse = query_b@key_w), queryT, upg — one launch
    prep_misc<<<4096, 256, 0, stream>>>(key_w, w_keyT, query_w, w_queryT,
                                        query_b, bfuse, up_w, w_upg);
    // WVU[v,td] = sum_h Wv[v,h]*upg[td,h]  (split-K x4)
    gemm_dense<<<dim3(8, 4, 4), 256, 0, stream>>>(
        w_value, w_upg, HID, HID / 4, prep, (size_t)HID * 512, 512);
    reduce_sk<<<512, 256, 0, stream>>>(prep, (size_t)HID * 512 / 4, 4,
                                       w_wvu, HID * 512 / 4);
    // WF[h,h'] = sum_q query_w[q,h]*key_w[q,h']  (split-K x4)
    gemm_dense<<<dim3(8, 8, 4), 256, 0, stream>>>(
        w_queryT, w_keyT, HID, HID / 4, prep, (size_t)HID * HID, 1024);
    reduce_sk<<<1024, 256, 0, stream>>>(prep, (size_t)HID * HID / 4, 4,
                                        w_fuseM, HID * HID / 4);
    // WG[td,h] = sum_h' upg[td,h']*WF[h,h']  (split-K x4)
    gemm_dense<<<dim3(4, 8, 4), 256, 0, stream>>>(
        w_upg, w_fuseM, HID, HID / 4, prep, (size_t)512 * HID, 1024);
    reduce_sk<<<512, 256, 0, stream>>>(prep, (size_t)512 * HID / 4, 4,
                                       w_wg, 512 * HID / 4);
    // WU, BVU, bg, cu (parallel: 2568 blocks)
    score_weights<<<2568, 256, 0, stream>>>(w_fuseM, w_value, w_upg, up_b,
                                            bfuse, WU, BVU, bg, cu);

    // dense partials: part[z] = hs_h @ dense_w^T  (K chunk per z)
    gemm_dense<<<dim3(32, 8, sk), 256, 0, stream>>>(
        hs_h, w_dense, IDIM, IDIM / sk, part, (size_t)TOK * HID, 1024);
    // h = sum partials + dense_b; ai = LN(h + it); pn = f16(h + it); h -> f16
    ln_fused<<<TOK, 256, 0, stream>>>(part, sk, dense_b, it, ln_g, ln_b,
                                      h_h, ai, pn);
    // dual: down = relu(ai @ w_down^T + down_b);  g = pn @ w_wg^T + bg
    gemm_w32<5><<<dim3(32, 8), 1024, 0, stream>>>(
        ai, w_down, HID, 512, nullptr, down, down_b, nullptr, nullptr, bg,
        pn, w_wg, g);
    // scores -> softmax over T -> probs, wdown = probs*down
    scores_softmax<<<TOK, 256, 0, stream>>>(pn, WU, cu, down, g, probs, wdown);
    // fuse = h@Wv^T + wdown@WVU^T + probs@BVU + it   (value-fold, one GEMM)
    gemm_w32<6><<<dim3(32, 8), 1024, 0, stream>>>(
        h_h, w_value, HID, HID, fuse, nullptr, nullptr, it, probs, BVU,
        wdown, w_wvu, nullptr);
    // out = LN(fuse)
    ln_out<<<TOK, 256, 0, stream>>>(fuse, ln_g, ln_b, outp);
}